// Round 5
// baseline (275.685 us; speedup 1.0000x reference)
//
#include <hip/hip_runtime.h>

// ---------------------------------------------------------------------------
// ActorCritic fused loss, MI355X.  T=8192, B=4096.
//   k_detect : mask dtype probe (int32 {0,1} vs 1-byte bool)
//   k_scan   : rewards -> chunk-local discounted sums S[256][B]  (1024 blocks,
//              global_load_lds ring R=8, counted vmcnt, no barriers)
//   k_fold   : S -> 16 group aggregates Sg[16][B]                (64 blocks)
//   k_gscan  : Sg -> group-entry carries Hg[16][B]               (4 blocks,
//              16-step register scan)
//   k_main   : prologue folds Hg + <=15 S rows -> chunk carry; then
//              global_load_lds-staged fused pass over all 5 streams
//              (ring R=3 x 5KB/wave, counted vmcnt, no barriers) -> 10 sums.
//   k_final  : closed-form losses.
// All reduction/scan orders fixed -> bitwise deterministic across replays.
// ---------------------------------------------------------------------------

constexpr int T    = 8192;
constexpr int B    = 4096;
constexpr int B4   = B / 4;           // 1024 float4 columns
constexpr int BLK  = 256;
constexpr int WAVES = BLK / 64;
constexpr int L    = 32;              // chunk length
constexpr int NC   = T / L;           // 256 chunks
constexpr int SL   = 4;               // column slices of 256 float4 cols
constexpr int NTILE = NC * SL;        // 1024 blocks for scan/main
constexpr int GSZ  = 16;              // chunks per group
constexpr int NGRP = NC / GSZ;        // 16 groups

constexpr float GAMMA_F = 0.99f;
constexpr double cpow(double g, int n) { double r = 1.0; for (int i = 0; i < n; ++i) r *= g; return r; }
constexpr float G32  = (float)cpow(0.99, L);        // gamma^32
constexpr float G512 = (float)cpow(0.99, L * GSZ);  // gamma^512

// wait until <= N VMEM ops outstanding (gfx9 encoding: vm[3:0],[15:14]; lgkm=15; exp=7)
#define WAITVM(N) __builtin_amdgcn_s_waitcnt(((N) & 15) | (((N) >> 4) << 14) | (15 << 8) | (7 << 4))

#define GLL16(GP, LP) __builtin_amdgcn_global_load_lds(                       \
    (const __attribute__((address_space(1))) void*)(GP),                      \
    (__attribute__((address_space(3))) void*)(LP), 16, 0, 0)
#define GLL4(GP, LP) __builtin_amdgcn_global_load_lds(                        \
    (const __attribute__((address_space(1))) void*)(GP),                      \
    (__attribute__((address_space(3))) void*)(LP), 4, 0, 0)

// --------------------------------------------------------------------------
__global__ void __launch_bounds__(BLK) k_detect(const unsigned char* __restrict__ m,
                                                int* __restrict__ flag) {
    __shared__ unsigned sh[WAVES];
    unsigned v = 0;
    for (int i = threadIdx.x; i < 65536; i += BLK)
        if (i & 3) v |= m[i];
    #pragma unroll
    for (int off = 32; off; off >>= 1) v |= __shfl_down(v, off);
    if ((threadIdx.x & 63) == 0) sh[threadIdx.x >> 6] = v;
    __syncthreads();
    if (threadIdx.x == 0) {
        unsigned r = 0;
        #pragma unroll
        for (int w = 0; w < WAVES; ++w) r |= sh[w];
        *flag = (r == 0) ? 1 : 0;   // 1 => int32 layout
    }
}

// --------------------------------------------------------------------------
#define ACC4(A_, R_)                         \
    do {                                     \
        A_.x = fmaf(GAMMA_F, A_.x, R_.x);    \
        A_.y = fmaf(GAMMA_F, A_.y, R_.y);    \
        A_.z = fmaf(GAMMA_F, A_.z, R_.z);    \
        A_.w = fmaf(GAMMA_F, A_.w, R_.w);    \
    } while (0)

#define AXPY4(X_, W_, S_)                    \
    do {                                     \
        X_.x = fmaf(W_, S_.x, X_.x);         \
        X_.y = fmaf(W_, S_.y, X_.y);         \
        X_.z = fmaf(W_, S_.z, X_.z);         \
        X_.w = fmaf(W_, S_.w, X_.w);         \
    } while (0)

#define FOLD4(H_, S_, W_)                    \
    do {                                     \
        H_.x = fmaf(W_, H_.x, S_.x);         \
        H_.y = fmaf(W_, H_.y, S_.y);         \
        H_.z = fmaf(W_, H_.z, S_.z);         \
        H_.w = fmaf(W_, H_.w, S_.w);         \
    } while (0)

// --------------------------------------------------------------------------
// k_scan: per (chunk, slice) block, DMA-staged rewards, Horner backward.
__global__ void __launch_bounds__(BLK) k_scan(const float4* __restrict__ rw,
                                              float4* __restrict__ S) {
    __shared__ char sm[WAVES * 8 * 1024];     // 32 KiB: 8-slot ring per wave
    const int tid = threadIdx.x, wv = tid >> 6, lane = tid & 63;
    const int bid = blockIdx.x, c = bid >> 2, s = bid & 3;
    const int b = s * 256 + tid;
    const int base = c * L * B4 + b;
    char* lw = sm + wv * 8192;

    #define SC_STAGE(i) GLL16(rw + base + (i) * B4, lw + ((i) & 7) * 1024)
    SC_STAGE(31); SC_STAGE(30); SC_STAGE(29); SC_STAGE(28);
    SC_STAGE(27); SC_STAGE(26); SC_STAGE(25);

    float4 a = make_float4(0.f, 0.f, 0.f, 0.f);
    #define SC_ROW(i)                                                         \
        do {                                                                  \
            if ((i) >= 7) SC_STAGE((i) - 7);                                  \
            WAITVM((i) >= 7 ? 7 : (i));                                       \
            __builtin_amdgcn_sched_barrier(0);                                \
            float4 r_ = *(const float4*)(lw + ((i) & 7) * 1024 + lane * 16);  \
            ACC4(a, r_);                                                      \
        } while (0)
    SC_ROW(31); SC_ROW(30); SC_ROW(29); SC_ROW(28); SC_ROW(27); SC_ROW(26);
    SC_ROW(25); SC_ROW(24); SC_ROW(23); SC_ROW(22); SC_ROW(21); SC_ROW(20);
    SC_ROW(19); SC_ROW(18); SC_ROW(17); SC_ROW(16); SC_ROW(15); SC_ROW(14);
    SC_ROW(13); SC_ROW(12); SC_ROW(11); SC_ROW(10); SC_ROW(9);  SC_ROW(8);
    SC_ROW(7);  SC_ROW(6);  SC_ROW(5);  SC_ROW(4);  SC_ROW(3);  SC_ROW(2);
    SC_ROW(1);  SC_ROW(0);

    S[(size_t)c * B4 + b] = a;
}

// --------------------------------------------------------------------------
// Sg[g] = sum_{j=0..15} G32^j * S[g*16+j]
__global__ void __launch_bounds__(BLK) k_fold(const float4* __restrict__ S,
                                              float4* __restrict__ Sg) {
    int idx = blockIdx.x * BLK + threadIdx.x;   // 0..16383
    int g = idx >> 10;
    int b = idx & 1023;
    float4 X = make_float4(0.f, 0.f, 0.f, 0.f);
    float w = 1.f;
    #pragma unroll
    for (int j = 0; j < GSZ; ++j) {
        float4 sv = S[(size_t)(g * GSZ + j) * B4 + b];
        AXPY4(X, w, sv);
        w *= G32;
    }
    Sg[(size_t)g * B4 + b] = X;
}

// Hg[g] = sum_{gg>g} G512^(gg-g-1) * Sg[gg]  (carry entering end of group g)
__global__ void __launch_bounds__(BLK) k_gscan(const float4* __restrict__ Sg,
                                               float4* __restrict__ Hg) {
    int b = blockIdx.x * BLK + threadIdx.x;     // 0..B4-1
    float4 sg[NGRP];
    #pragma unroll
    for (int g = 0; g < NGRP; ++g) sg[g] = Sg[(size_t)g * B4 + b];
    float4 h = make_float4(0.f, 0.f, 0.f, 0.f);
    #pragma unroll
    for (int g = NGRP - 1; g >= 0; --g) {
        Hg[(size_t)g * B4 + b] = h;
        FOLD4(h, sg[g], G512);
    }
}

// --------------------------------------------------------------------------
#define COMP(MJ, GX, RX, VX, LX, ZX)                 \
    do {                                             \
        GX = fmaf(GAMMA_F, GX, RX);                  \
        float mm = (MJ);                             \
        float Gm = mm * GX, vm = mm * VX, lm = mm * LX; \
        a[0] += mm; a[1] += Gm;                      \
        a[2] = fmaf(Gm, GX, a[2]);                   \
        a[3] = fmaf(Gm, VX, a[3]);                   \
        a[4] += vm; a[5] = fmaf(vm, VX, a[5]);       \
        a[6] = fmaf(lm, GX, a[6]); a[7] += lm;       \
        a[8] = fmaf(mm, ZX, a[8]);                   \
        a[9] = fmaf(lm, VX, a[9]);                   \
    } while (0)

constexpr int RNG  = 3;        // ring depth (rows in flight = 2)
constexpr int SLOT = 5 * 1024; // 4 f32 arrays + mask, 1 KiB each per wave-row

template<bool I32>
__device__ __forceinline__ void stage_row(const float4* __restrict__ rw,
                                          const float4* __restrict__ vv,
                                          const float4* __restrict__ lq,
                                          const float4* __restrict__ en,
                                          const void*  __restrict__ mp,
                                          int base, int i, char* lw) {
    char* lb = lw + (i % RNG) * SLOT;
    GLL16(rw + base + i * B4, lb);
    GLL16(vv + base + i * B4, lb + 1024);
    GLL16(lq + base + i * B4, lb + 2048);
    GLL16(en + base + i * B4, lb + 3072);
    if constexpr (I32) GLL16((const int4*)mp + base + i * B4, lb + 4096);
    else               GLL4((const uchar4*)mp + base + i * B4, lb + 4096);
}

template<bool I32>
__device__ __forceinline__ void comp_row(int i, const char* lw, int lane,
                                         float4& G, float a[10]) {
    const char* lb = lw + (i % RNG) * SLOT;
    float4 r = *(const float4*)(lb + lane * 16);
    float4 v = *(const float4*)(lb + 1024 + lane * 16);
    float4 l = *(const float4*)(lb + 2048 + lane * 16);
    float4 z = *(const float4*)(lb + 3072 + lane * 16);
    float m0, m1, m2, m3;
    if constexpr (I32) {
        int4 q = *(const int4*)(lb + 4096 + lane * 16);
        m0 = q.x ? 1.f : 0.f; m1 = q.y ? 1.f : 0.f;
        m2 = q.z ? 1.f : 0.f; m3 = q.w ? 1.f : 0.f;
    } else {
        uchar4 u = *(const uchar4*)(lb + 4096 + lane * 4);
        m0 = u.x ? 1.f : 0.f; m1 = u.y ? 1.f : 0.f;
        m2 = u.z ? 1.f : 0.f; m3 = u.w ? 1.f : 0.f;
    }
    COMP(m0, G.x, r.x, v.x, l.x, z.x);
    COMP(m1, G.y, r.y, v.y, l.y, z.y);
    COMP(m2, G.z, r.z, v.z, l.z, z.z);
    COMP(m3, G.w, r.w, v.w, l.w, z.w);
}

template<bool I32>
__device__ __forceinline__ void run_rows(const float4* __restrict__ rw,
                                         const float4* __restrict__ vv,
                                         const float4* __restrict__ lq,
                                         const float4* __restrict__ en,
                                         const void*  __restrict__ mp,
                                         int base, char* lw, int lane,
                                         float4& G, float a[10]) {
    stage_row<I32>(rw, vv, lq, en, mp, base, 31, lw);
    stage_row<I32>(rw, vv, lq, en, mp, base, 30, lw);
    #define ROWM(i)                                                           \
        do {                                                                  \
            if ((i) >= 2) stage_row<I32>(rw, vv, lq, en, mp, base, (i) - 2, lw); \
            WAITVM((i) >= 2 ? 10 : 5 * (i));                                  \
            __builtin_amdgcn_sched_barrier(0);                                \
            comp_row<I32>((i), lw, lane, G, a);                               \
        } while (0)
    ROWM(31); ROWM(30); ROWM(29); ROWM(28); ROWM(27); ROWM(26);
    ROWM(25); ROWM(24); ROWM(23); ROWM(22); ROWM(21); ROWM(20);
    ROWM(19); ROWM(18); ROWM(17); ROWM(16); ROWM(15); ROWM(14);
    ROWM(13); ROWM(12); ROWM(11); ROWM(10); ROWM(9);  ROWM(8);
    ROWM(7);  ROWM(6);  ROWM(5);  ROWM(4);  ROWM(3);  ROWM(2);
    ROWM(1);  ROWM(0);
}

__global__ void __launch_bounds__(BLK) k_main(const float4* __restrict__ rw,
                                              const float4* __restrict__ vv,
                                              const float4* __restrict__ lq,
                                              const float4* __restrict__ en,
                                              const void*  __restrict__ mp,
                                              const int*   __restrict__ flag,
                                              const float4* __restrict__ S,
                                              const float4* __restrict__ Hg,
                                              double* __restrict__ partials) {
    __shared__ char sm[WAVES * RNG * SLOT];   // 60 KiB
    const int tid = threadIdx.x, wv = tid >> 6, lane = tid & 63;
    const int bid = blockIdx.x, c = bid >> 2, s = bid & 3;
    const int b = s * 256 + tid;
    const int base = c * L * B4 + b;
    const int g = c >> 4;
    const int gend = (g << 4) | (GSZ - 1);
    char* lw = sm + wv * (RNG * SLOT);

    // prologue: chunk-entry carry  X = sum_{cc>c within group} G32^(cc-c-1)*S[cc]
    //                                  + G32^(gend-c)*Hg[g]
    float4 X = make_float4(0.f, 0.f, 0.f, 0.f);
    float w = 1.f;
    for (int cc = c + 1; cc <= gend; ++cc) {
        float4 sv = S[(size_t)cc * B4 + b];
        AXPY4(X, w, sv);
        w *= G32;
    }
    float4 hg = Hg[(size_t)g * B4 + b];
    AXPY4(X, w, hg);
    float4 G = X;

    float a[10] = {0.f, 0.f, 0.f, 0.f, 0.f, 0.f, 0.f, 0.f, 0.f, 0.f};
    if (*flag) run_rows<true >(rw, vv, lq, en, mp, base, lw, lane, G, a);
    else       run_rows<false>(rw, vv, lq, en, mp, base, lw, lane, G, a);

    // deterministic block reduction in f64
    double d[10];
    #pragma unroll
    for (int k = 0; k < 10; ++k) d[k] = (double)a[k];
    #pragma unroll
    for (int k = 0; k < 10; ++k)
        #pragma unroll
        for (int off = 32; off; off >>= 1)
            d[k] += __shfl_down(d[k], off);

    __shared__ double sh[WAVES][10];
    if (lane == 0) {
        #pragma unroll
        for (int k = 0; k < 10; ++k) sh[wv][k] = d[k];
    }
    __syncthreads();
    if (tid == 0) {
        #pragma unroll
        for (int k = 0; k < 10; ++k) {
            double t = sh[0][k];
            #pragma unroll
            for (int ww = 1; ww < WAVES; ++ww) t += sh[ww][k];
            partials[(size_t)bid * 10 + k] = t;
        }
    }
}

// --------------------------------------------------------------------------
__global__ void __launch_bounds__(BLK) k_final(const double* __restrict__ partials,
                                               float* __restrict__ out) {
    double d[10];
    #pragma unroll
    for (int k = 0; k < 10; ++k) d[k] = 0.0;
    for (int i = threadIdx.x; i < NTILE; i += BLK) {
        #pragma unroll
        for (int k = 0; k < 10; ++k) d[k] += partials[(size_t)i * 10 + k];
    }
    #pragma unroll
    for (int k = 0; k < 10; ++k)
        #pragma unroll
        for (int off = 32; off; off >>= 1)
            d[k] += __shfl_down(d[k], off);

    __shared__ double sh[WAVES][10];
    int lane = threadIdx.x & 63, wv = threadIdx.x >> 6;
    if (lane == 0) {
        #pragma unroll
        for (int k = 0; k < 10; ++k) sh[wv][k] = d[k];
    }
    __syncthreads();
    if (threadIdx.x == 0) {
        double s[10];
        #pragma unroll
        for (int k = 0; k < 10; ++k) {
            double t = sh[0][k];
            #pragma unroll
            for (int ww = 1; ww < WAVES; ++ww) t += sh[ww][k];
            s[k] = t;
        }
        double n = s[0], SG = s[1], SG2 = s[2], SGv = s[3], Sv = s[4];
        double Sv2 = s[5], SlpG = s[6], Slp = s[7], Sent = s[8], Slpv = s[9];

        double mean = SG / n;
        double css  = SG2 - 2.0 * mean * SG + mean * mean * n;  // sum m*(G-mean)^2
        double var  = css / (n - 1.0);
        double sd   = sqrt(var);
        double sc   = 1.0 / (sd + 1e-8);

        double critic = sc * sc * css - 2.0 * sc * (SGv - mean * Sv) + Sv2;
        double actor  = -sc * (SlpG - mean * Slp) + Slpv - 0.01 * Sent;

        out[0] = (float)critic;
        out[1] = (float)actor;
    }
}

// --------------------------------------------------------------------------
extern "C" void kernel_launch(void* const* d_in, const int* in_sizes, int n_in,
                              void* d_out, int out_size, void* d_ws, size_t ws_size,
                              hipStream_t stream) {
    const float4* rw = (const float4*)d_in[0];
    const float4* vv = (const float4*)d_in[1];
    const float4* lq = (const float4*)d_in[2];
    const float4* en = (const float4*)d_in[3];
    const void*   mp = d_in[4];

    char* ws = (char*)d_ws;
    size_t off = 0;
    float4* S  = (float4*)(ws + off); off += (size_t)NC   * B4 * 16;  // 4 MiB
    float4* Sg = (float4*)(ws + off); off += (size_t)NGRP * B4 * 16;  // 256 KiB
    float4* Hg = (float4*)(ws + off); off += (size_t)NGRP * B4 * 16;  // 256 KiB
    double* p1 = (double*)(ws + off); off += (size_t)NTILE * 10 * 8;  // 80 KiB
    int*  flag = (int*)  (ws + off);

    k_detect<<<1, BLK, 0, stream>>>((const unsigned char*)mp, flag);
    k_scan  <<<NTILE, BLK, 0, stream>>>(rw, S);
    k_fold  <<<NGRP * B4 / BLK, BLK, 0, stream>>>(S, Sg);
    k_gscan <<<B4 / BLK, BLK, 0, stream>>>(Sg, Hg);
    k_main  <<<NTILE, BLK, 0, stream>>>(rw, vv, lq, en, mp, flag, S, Hg, p1);
    k_final <<<1, BLK, 0, stream>>>(p1, (float*)d_out);
}

// Round 7
// 231.004 us; speedup vs baseline: 1.1934x; 1.1934x over previous
//
#include <hip/hip_runtime.h>
#include <hip/hip_cooperative_groups.h>

namespace cg = cooperative_groups;

// ---------------------------------------------------------------------------
// ActorCritic fused loss, MI355X.  T=8192, B=4096.
// Preferred: ONE cooperative kernel (3 grid.sync()s):
//   phase1: chunk-local discounted sums S[256][B] (dual-chain Horner) + probe
//   phase2: blocks 0..3: backward 256-step column scan S -> per-chunk carry H
//   phase3: fused masked pass over 5 streams using H -> 10 block partials
//   phase4: block 0: reduce partials, closed-form losses.
// Fallback (if coop gate/launch refuses): same phases as 4 dispatches.
// Host gate: hipDeviceAttributeCooperativeLaunch + occupancy query (both
// capture-safe host queries) + launch-retcode check.
// All FP orders fixed -> bitwise deterministic across replays.
// ---------------------------------------------------------------------------

constexpr int T     = 8192;
constexpr int B     = 4096;
constexpr int B4    = B / 4;          // 1024 float4 columns
constexpr int BLK   = 256;
constexpr int WAVES = BLK / 64;
constexpr int L     = 32;             // chunk length
constexpr int NC    = T / L;          // 256 chunks
constexpr int NTILE = NC * 4;         // 1024 blocks (4 column slices)

constexpr float GAMMA_F = 0.99f;
constexpr double cpow(double g, int n) { double r = 1.0; for (int i = 0; i < n; ++i) r *= g; return r; }
constexpr float G32 = (float)cpow(0.99, L);   // gamma^32

// --------------------------------------------------------------------------
#define COMP(MJ, GX, RX, VX, LX, ZX)                 \
    do {                                             \
        GX = fmaf(GAMMA_F, GX, RX);                  \
        float mm = (MJ);                             \
        float Gm = mm * GX, vm = mm * VX, lm = mm * LX; \
        a[0] += mm; a[1] += Gm;                      \
        a[2] = fmaf(Gm, GX, a[2]);                   \
        a[3] = fmaf(Gm, VX, a[3]);                   \
        a[4] += vm; a[5] = fmaf(vm, VX, a[5]);       \
        a[6] = fmaf(lm, GX, a[6]); a[7] += lm;       \
        a[8] = fmaf(mm, ZX, a[8]);                   \
        a[9] = fmaf(lm, VX, a[9]);                   \
    } while (0)

#define MASK_I32 { int4 q = ((const int4*)mp)[e]; \
    m0 = q.x ? 1.f : 0.f; m1 = q.y ? 1.f : 0.f; m2 = q.z ? 1.f : 0.f; m3 = q.w ? 1.f : 0.f; }
#define MASK_U8  { uchar4 q = ((const uchar4*)mp)[e]; \
    m0 = q.x ? 1.f : 0.f; m1 = q.y ? 1.f : 0.f; m2 = q.z ? 1.f : 0.f; m3 = q.w ? 1.f : 0.f; }

#define ITER_BODY(MASKLOAD)                          \
    _Pragma("unroll 4")                              \
    for (int i = L - 1; i >= 0; --i) {               \
        int e = base + i * B4;                       \
        float4 r = rw[e], v = vv[e], l = lq[e], z = en[e]; \
        float m0, m1, m2, m3;                        \
        MASKLOAD;                                    \
        COMP(m0, G.x, r.x, v.x, l.x, z.x);           \
        COMP(m1, G.y, r.y, v.y, l.y, z.y);           \
        COMP(m2, G.z, r.z, v.z, l.z, z.z);           \
        COMP(m3, G.w, r.w, v.w, l.w, z.w);           \
    }

// dual-chain Horner: G = E + gamma*O, chains step by gamma^2 (half the
// dependent-FMA depth of the naive Horner; all 32 loads independent).
__device__ __forceinline__ float4 chunk_scan(const float4* __restrict__ rw, int base) {
    const float g2 = GAMMA_F * GAMMA_F;
    float4 e4 = make_float4(0.f, 0.f, 0.f, 0.f);
    float4 o4 = make_float4(0.f, 0.f, 0.f, 0.f);
    #pragma unroll
    for (int j = L / 2 - 1; j >= 0; --j) {
        float4 ro = rw[base + (2 * j + 1) * B4];
        float4 re = rw[base + (2 * j) * B4];
        o4.x = fmaf(g2, o4.x, ro.x); o4.y = fmaf(g2, o4.y, ro.y);
        o4.z = fmaf(g2, o4.z, ro.z); o4.w = fmaf(g2, o4.w, ro.w);
        e4.x = fmaf(g2, e4.x, re.x); e4.y = fmaf(g2, e4.y, re.y);
        e4.z = fmaf(g2, e4.z, re.z); e4.w = fmaf(g2, e4.w, re.w);
    }
    float4 s;
    s.x = fmaf(GAMMA_F, o4.x, e4.x); s.y = fmaf(GAMMA_F, o4.y, e4.y);
    s.z = fmaf(GAMMA_F, o4.z, e4.z); s.w = fmaf(GAMMA_F, o4.w, e4.w);
    return s;
}

// backward carry scan for one column: H[c] = carry entering chunk c
__device__ __forceinline__ void carry_col(const float4* __restrict__ S,
                                          float4* __restrict__ H, int col) {
    float4 h = make_float4(0.f, 0.f, 0.f, 0.f);
    #pragma unroll 8
    for (int cc = NC - 1; cc >= 0; --cc) {
        H[(size_t)cc * B4 + col] = h;
        float4 s2 = S[(size_t)cc * B4 + col];
        h.x = fmaf(G32, h.x, s2.x); h.y = fmaf(G32, h.y, s2.y);
        h.z = fmaf(G32, h.z, s2.z); h.w = fmaf(G32, h.w, s2.w);
    }
}

__device__ __forceinline__ void block_reduce10(float a[10], double* dst,
                                               double shd[WAVES][10],
                                               int tid) {
    double d[10];
    #pragma unroll
    for (int k = 0; k < 10; ++k) d[k] = (double)a[k];
    #pragma unroll
    for (int k = 0; k < 10; ++k)
        #pragma unroll
        for (int off = 32; off; off >>= 1)
            d[k] += __shfl_down(d[k], off);
    int lane = tid & 63, wv = tid >> 6;
    if (lane == 0) {
        #pragma unroll
        for (int k = 0; k < 10; ++k) shd[wv][k] = d[k];
    }
    __syncthreads();
    if (tid == 0) {
        #pragma unroll
        for (int k = 0; k < 10; ++k) {
            double t = shd[0][k];
            #pragma unroll
            for (int ww = 1; ww < WAVES; ++ww) t += shd[ww][k];
            dst[k] = t;
        }
    }
}

__device__ __forceinline__ void finalize(const double s[10], float* out) {
    double n = s[0], SG = s[1], SG2 = s[2], SGv = s[3], Sv = s[4];
    double Sv2 = s[5], SlpG = s[6], Slp = s[7], Sent = s[8], Slpv = s[9];
    double mean = SG / n;
    double css  = SG2 - 2.0 * mean * SG + mean * mean * n;  // sum m*(G-mean)^2
    double var  = css / (n - 1.0);
    double sd   = sqrt(var);
    double sc   = 1.0 / (sd + 1e-8);
    double critic = sc * sc * css - 2.0 * sc * (SGv - mean * Sv) + Sv2;
    double actor  = -sc * (SlpG - mean * Slp) + Slpv - 0.01 * Sent;
    out[0] = (float)critic;
    out[1] = (float)actor;
}

__device__ __forceinline__ void final_reduce(const double* __restrict__ p1,
                                             double shd[WAVES][10],
                                             int tid, float* out) {
    double d[10];
    #pragma unroll
    for (int k = 0; k < 10; ++k) d[k] = 0.0;
    for (int i = tid; i < NTILE; i += BLK) {
        #pragma unroll
        for (int k = 0; k < 10; ++k) d[k] += p1[(size_t)i * 10 + k];
    }
    #pragma unroll
    for (int k = 0; k < 10; ++k)
        #pragma unroll
        for (int off = 32; off; off >>= 1)
            d[k] += __shfl_down(d[k], off);
    int lane = tid & 63, wv = tid >> 6;
    if (lane == 0) {
        #pragma unroll
        for (int k = 0; k < 10; ++k) shd[wv][k] = d[k];
    }
    __syncthreads();
    if (tid == 0) {
        double s[10];
        #pragma unroll
        for (int k = 0; k < 10; ++k) {
            double t = shd[0][k];
            #pragma unroll
            for (int ww = 1; ww < WAVES; ++ww) t += shd[ww][k];
            s[k] = t;
        }
        finalize(s, out);
    }
}

// probe: int32 {0,1} layout has bytes 1..3 of every element == 0
__device__ __forceinline__ void mask_probe(const unsigned char* __restrict__ m8,
                                           unsigned shp[WAVES], int tid,
                                           int* __restrict__ dflag) {
    unsigned vbits = 0;
    for (int i = tid; i < 65536; i += BLK)
        if (i & 3) vbits |= m8[i];
    #pragma unroll
    for (int off = 32; off; off >>= 1) vbits |= __shfl_down(vbits, off);
    if ((tid & 63) == 0) shp[tid >> 6] = vbits;
    __syncthreads();
    if (tid == 0) {
        unsigned r = 0;
        #pragma unroll
        for (int w = 0; w < WAVES; ++w) r |= shp[w];
        *dflag = (r == 0) ? 1 : 0;   // 1 => int32 layout
    }
}

// ==========================================================================
// Cooperative single-launch kernel
__global__ void __launch_bounds__(BLK, 4) k_all(
    const float4* __restrict__ rw, const float4* __restrict__ vv,
    const float4* __restrict__ lq, const float4* __restrict__ en,
    const void*  __restrict__ mp,
    float4* __restrict__ S, float4* __restrict__ H,
    double* __restrict__ p1, int* __restrict__ dflag, float* __restrict__ out)
{
    cg::grid_group grid = cg::this_grid();
    const int tid = threadIdx.x;
    const int bid = blockIdx.x;
    const int c = bid >> 2, s = bid & 3;
    const int b = s * 256 + tid;
    const int base = c * L * B4 + b;

    __shared__ double shd[WAVES][10];
    __shared__ unsigned shp[WAVES];

    // phase 1: chunk sums + mask probe
    S[(size_t)c * B4 + b] = chunk_scan(rw, base);
    if (bid == NTILE - 1) mask_probe((const unsigned char*)mp, shp, tid, dflag);
    grid.sync();

    // phase 2: per-chunk carries (blocks 0..3)
    if (bid < B4 / BLK) carry_col(S, H, bid * BLK + tid);
    grid.sync();

    // phase 3: fused masked pass
    {
        float4 G = H[(size_t)c * B4 + b];
        float a[10] = {0.f, 0.f, 0.f, 0.f, 0.f, 0.f, 0.f, 0.f, 0.f, 0.f};
        if (*dflag) { ITER_BODY(MASK_I32); }
        else        { ITER_BODY(MASK_U8); }
        block_reduce10(a, p1 + (size_t)bid * 10, shd, tid);
    }
    grid.sync();

    // phase 4: final
    if (bid == 0) final_reduce(p1, shd, tid, out);
}

// ==========================================================================
// Fallback pipeline (4 dispatches)
__global__ void __launch_bounds__(BLK) k_scanf(const float4* __restrict__ rw,
                                               const void* __restrict__ mp,
                                               float4* __restrict__ S,
                                               int* __restrict__ dflag) {
    __shared__ unsigned shp[WAVES];
    const int tid = threadIdx.x, bid = blockIdx.x;
    const int c = bid >> 2, s = bid & 3;
    const int b = s * 256 + tid;
    S[(size_t)c * B4 + b] = chunk_scan(rw, c * L * B4 + b);
    if (bid == NTILE - 1) mask_probe((const unsigned char*)mp, shp, tid, dflag);
}

__global__ void __launch_bounds__(BLK) k_carryf(const float4* __restrict__ S,
                                                float4* __restrict__ H) {
    carry_col(S, H, blockIdx.x * BLK + threadIdx.x);
}

__global__ void __launch_bounds__(BLK) k_mainf(const float4* __restrict__ rw,
                                               const float4* __restrict__ vv,
                                               const float4* __restrict__ lq,
                                               const float4* __restrict__ en,
                                               const void*  __restrict__ mp,
                                               const int*   __restrict__ dflag,
                                               const float4* __restrict__ H,
                                               double* __restrict__ p1) {
    __shared__ double shd[WAVES][10];
    const int tid = threadIdx.x, bid = blockIdx.x;
    const int c = bid >> 2, s = bid & 3;
    const int b = s * 256 + tid;
    const int base = c * L * B4 + b;
    float4 G = H[(size_t)c * B4 + b];
    float a[10] = {0.f, 0.f, 0.f, 0.f, 0.f, 0.f, 0.f, 0.f, 0.f, 0.f};
    if (*dflag) { ITER_BODY(MASK_I32); }
    else        { ITER_BODY(MASK_U8); }
    block_reduce10(a, p1 + (size_t)bid * 10, shd, tid);
}

__global__ void __launch_bounds__(BLK) k_finalf(const double* __restrict__ p1,
                                                float* __restrict__ out) {
    __shared__ double shd[WAVES][10];
    final_reduce(p1, shd, threadIdx.x, out);
}

// ==========================================================================
extern "C" void kernel_launch(void* const* d_in, const int* in_sizes, int n_in,
                              void* d_out, int out_size, void* d_ws, size_t ws_size,
                              hipStream_t stream) {
    const float4* rw = (const float4*)d_in[0];
    const float4* vv = (const float4*)d_in[1];
    const float4* lq = (const float4*)d_in[2];
    const float4* en = (const float4*)d_in[3];
    const void*   mp = d_in[4];

    char* ws = (char*)d_ws;
    size_t off = 0;
    float4* S   = (float4*)(ws + off); off += (size_t)NC * B4 * 16;   // 4 MiB
    float4* H   = (float4*)(ws + off); off += (size_t)NC * B4 * 16;   // 4 MiB
    double* p1  = (double*)(ws + off); off += (size_t)NTILE * 10 * 8; // 80 KiB
    int*  dflag = (int*)  (ws + off);
    float* outp = (float*)d_out;

    // capture-safe host queries: decide cooperative vs fallback
    int dev = 0;
    (void)hipGetDevice(&dev);
    int coop = 0, ncu = 0, maxb = 0;
    (void)hipDeviceGetAttribute(&coop, hipDeviceAttributeCooperativeLaunch, dev);
    (void)hipDeviceGetAttribute(&ncu, hipDeviceAttributeMultiprocessorCount, dev);
    bool use_coop = false;
    if (coop) {
        if (hipOccupancyMaxActiveBlocksPerMultiprocessor(&maxb, k_all, BLK, 0)
                == hipSuccess && (long)maxb * ncu >= NTILE)
            use_coop = true;
    }
    if (use_coop) {
        void* args[] = { (void*)&rw, (void*)&vv, (void*)&lq, (void*)&en,
                         (void*)&mp, (void*)&S, (void*)&H, (void*)&p1,
                         (void*)&dflag, (void*)&outp };
        if (hipLaunchCooperativeKernel((void*)k_all, dim3(NTILE), dim3(BLK),
                                       args, 0, stream) != hipSuccess)
            use_coop = false;
    }
    if (!use_coop) {
        k_scanf <<<NTILE, BLK, 0, stream>>>(rw, mp, S, dflag);
        k_carryf<<<B4 / BLK, BLK, 0, stream>>>(S, H);
        k_mainf <<<NTILE, BLK, 0, stream>>>(rw, vv, lq, en, mp, dflag, H, p1);
        k_finalf<<<1, BLK, 0, stream>>>(p1, outp);
    }
}